// Round 12
// baseline (229.833 us; speedup 1.0000x reference)
//
#include <hip/hip_runtime.h>
#include <hip/hip_bf16.h>
#include <math.h>

#define NROWS 2048
#define HD 512
#define DBx 128

typedef __attribute__((ext_vector_type(8)))  short bf16x8;
typedef __attribute__((ext_vector_type(4)))  float f32x4;
typedef __attribute__((ext_vector_type(16))) float f32x16;

__device__ inline unsigned pack2_bf16(float a, float b) {
    union { __hip_bfloat162 h; unsigned u; } cv;
    cv.h = __float22bfloat162_rn(make_float2(a, b));
    return cv.u;
}
__device__ inline unsigned short pack1_bf16(float a) {
    union { __hip_bfloat16 h; unsigned short u; } cv;
    cv.h = __float2bfloat16(a);
    return cv.u;
}

// ---------------------------------------------------------------------------
// All 6 weight transposes (f32 [K][M] -> bf16 [M][K]) + input f32->bf16
// conversion (tail block range) in ONE kernel.
// ---------------------------------------------------------------------------
struct TransArgs {
    const float* src[6];
    unsigned short* dst[6];
    int K[6], M[6], t0[6];
};
#define TRANS_BLOCKS 7424
#define CONV_BLOCKS  1024

__global__ __launch_bounds__(256) void trans_all_kernel(TransArgs a,
                                                        const float* __restrict__ cin,
                                                        unsigned short* __restrict__ cout) {
    const int id = blockIdx.x;
    if (id >= TRANS_BLOCKS) {
        // input conversion: 2048*512 f32 -> bf16, 1 float4 per thread
        const int idx = (id - TRANS_BLOCKS) * 256 + threadIdx.x;   // < 262144
        const float4 v = *reinterpret_cast<const float4*>(cin + (size_t)idx * 4);
        uint2 o;
        o.x = pack2_bf16(v.x, v.y);
        o.y = pack2_bf16(v.z, v.w);
        *reinterpret_cast<uint2*>(cout + (size_t)idx * 4) = o;
        return;
    }
    int m = 0;
    #pragma unroll
    for (int q = 1; q < 6; ++q) if (id >= a.t0[q]) m = q;
    const int local = id - a.t0[m];
    const int M = a.M[m], K = a.K[m];
    const int ntm = M >> 5;
    const int mt = local % ntm;
    const int kt = local / ntm;
    const float* W = a.src[m];
    unsigned short* Wt = a.dst[m];

    __shared__ float tile[32][33];
    const int t  = threadIdx.x;
    const int tr = t >> 3;
    const int tc = t & 7;
    const int k0 = kt * 32;
    const int m0 = mt * 32;

    const float4 v = *reinterpret_cast<const float4*>(&W[(size_t)(k0 + tr) * M + m0 + tc * 4]);
    tile[tr][tc * 4 + 0] = v.x;
    tile[tr][tc * 4 + 1] = v.y;
    tile[tr][tc * 4 + 2] = v.z;
    tile[tr][tc * 4 + 3] = v.w;
    __syncthreads();

    const float x = tile[tc * 4 + 0][tr];
    const float y = tile[tc * 4 + 1][tr];
    const float z = tile[tc * 4 + 2][tr];
    const float w = tile[tc * 4 + 3][tr];
    uint2 o;
    o.x = pack2_bf16(x, y);
    o.y = pack2_bf16(z, w);
    *reinterpret_cast<uint2*>(&Wt[(size_t)(m0 + tr) * K + k0 + tc * 4]) = o;
}

// ---------------------------------------------------------------------------
// bf16 MFMA GEMM, 64x64 tile, BK=64, 4 waves (2x2), 2-phase double-buffered
// global_load_lds pipeline. A bf16 [rows][K], Bt bf16 [M][K].
// XOR 16B-chunk swizzle ch^(row&7).
// MSB: additionally write bf16 C in per-b layout Msb[(col>>4)][row][col&15].
// ---------------------------------------------------------------------------
template<int WRITE_BF16, int WRITE_F32, int RELU, int BIAS, int MSB>
__global__ __launch_bounds__(256) void gemm64_kernel(const unsigned short* __restrict__ Abf,
                                                     const unsigned short* __restrict__ Bt,
                                                     const float* __restrict__ bias,
                                                     unsigned short* __restrict__ Cbf,
                                                     float* __restrict__ Cf,
                                                     int K, int M) {
    __shared__ unsigned short As[2][64 * 64];
    __shared__ unsigned short Bs[2][64 * 64];

    const int t    = threadIdx.x;
    const int lane = t & 63;
    const int wv   = t >> 6;
    const int wm   = wv & 1;
    const int wn   = wv >> 1;
    const int row0 = blockIdx.y * 64;
    const int col0 = blockIdx.x * 64;
    const int gl_r = lane >> 3;
    const int gl_c = lane & 7;

    f32x4 acc[2][2] = {};

    auto STAGE = [&](int bufi, int kt) {
        #pragma unroll
        for (int q = 0; q < 2; ++q) {
            const int r = wv * 16 + q * 8 + gl_r;
            const unsigned short* srcA = Abf + (size_t)(row0 + r) * K + kt + 8 * (gl_c ^ (r & 7));
            __builtin_amdgcn_global_load_lds(
                (const __attribute__((address_space(1))) void*)srcA,
                (__attribute__((address_space(3))) void*)(&As[bufi][(wv * 16 + q * 8) * 64]),
                16, 0, 0);
            const unsigned short* srcB = Bt + (size_t)(col0 + r) * K + kt + 8 * (gl_c ^ (r & 7));
            __builtin_amdgcn_global_load_lds(
                (const __attribute__((address_space(1))) void*)srcB,
                (__attribute__((address_space(3))) void*)(&Bs[bufi][(wv * 16 + q * 8) * 64]),
                16, 0, 0);
        }
    };

    const int nkt = K >> 6;
    STAGE(0, 0);
    __syncthreads();
    int buf = 0;
    for (int kt = 0; kt < nkt; ++kt) {
        if (kt + 1 < nkt) STAGE(buf ^ 1, (kt + 1) * 64);
        const int lm = lane & 15;
        const int kg = lane >> 4;
        #pragma unroll
        for (int ks = 0; ks < 2; ++ks) {
            bf16x8 af[2], bfr[2];
            #pragma unroll
            for (int fi = 0; fi < 2; ++fi) {
                const int r  = wm * 32 + fi * 16 + lm;
                const int ch = (kg + 4 * ks) ^ (r & 7);
                af[fi] = *reinterpret_cast<const bf16x8*>((const char*)&As[buf][0] + r * 128 + ch * 16);
            }
            #pragma unroll
            for (int fj = 0; fj < 2; ++fj) {
                const int n  = wn * 32 + fj * 16 + lm;
                const int ch = (kg + 4 * ks) ^ (n & 7);
                bfr[fj] = *reinterpret_cast<const bf16x8*>((const char*)&Bs[buf][0] + n * 128 + ch * 16);
            }
            #pragma unroll
            for (int fi = 0; fi < 2; ++fi)
                #pragma unroll
                for (int fj = 0; fj < 2; ++fj)
                    acc[fi][fj] = __builtin_amdgcn_mfma_f32_16x16x32_bf16(
                        af[fi], bfr[fj], acc[fi][fj], 0, 0, 0);
        }
        __syncthreads();
        buf ^= 1;
    }

    const int lm = lane & 15;
    const int lq = lane >> 4;
    #pragma unroll
    for (int fj = 0; fj < 2; ++fj) {
        const int col = col0 + wn * 32 + fj * 16 + lm;
        const float bv = BIAS ? bias[col] : 0.f;
        #pragma unroll
        for (int fi = 0; fi < 2; ++fi) {
            #pragma unroll
            for (int r = 0; r < 4; ++r) {
                const int row = row0 + wm * 32 + fi * 16 + lq * 4 + r;
                float v = acc[fi][fj][r] + bv;
                if (RELU) v = fmaxf(v, 0.f);
                if (WRITE_F32)  Cf[(size_t)row * M + col] = v;
                if (WRITE_BF16) {
                    if (MSB)
                        Cbf[(size_t)(col >> 4) * (NROWS * 16) + (size_t)row * 16 + (col & 15)] = pack1_bf16(v);
                    else
                        Cbf[(size_t)row * M + col] = pack1_bf16(v);
                }
            }
        }
    }
}

// ---------------------------------------------------------------------------
// Row norms (scaled 0.495) + init outT to 1.0 (exact j==i diagonal term).
// ---------------------------------------------------------------------------
__global__ __launch_bounds__(256) void norms_kernel(const float* __restrict__ Ms,
                                                    float* __restrict__ nrm,
                                                    float* __restrict__ oT) {
    const int g = blockIdx.x * 256 + threadIdx.x;
    const int i = g >> 7;
    const int b = g & 127;
    const float* p = Ms + (size_t)i * 2048 + b * 16;
    float s = 0.f;
    #pragma unroll
    for (int c = 0; c < 16; c += 4) {
        const float4 v = *reinterpret_cast<const float4*>(p + c);
        s += v.x * v.x + v.y * v.y + v.z * v.z + v.w * v.w;
    }
    nrm[(size_t)b * 2048 + i] = 0.495f * s;
    oT[g] = 1.0f;
}

// ---------------------------------------------------------------------------
// MFMA-gated minibatch discrimination v7 = v6 + TRIANGULAR symmetry.
// d(i,j)=d(j,i): evaluate each unordered pair once, add exp to BOTH rows.
// Coverage (proof in journal): pair {a<b}: both<1024 -> block(0,0); both>=1024
// -> (1,1); straddling -> (0,1)+(1,0) which split i-chunks 0-15 / 16-31 of
// [0,1024) against j in [1024,2048). Diagonal blocks sweep tiles jt>=q with
// element filter j>i; per-wave i-chunk sets {w,15-w,16+w,31-w} -> 66 tiles
// per wave (cross blocks: 64) -> balanced. j-slab select: jh = bx|bz.
// Gate (R4-proven): acc = dot + 725 - 0.495 n_i; pass iff acc[r] > 0.495 n_j.
// j==i term exp(0)=1 pre-added in outT init. Tile work halves: 4096->2080/b.
// ---------------------------------------------------------------------------
__global__ __launch_bounds__(512) void mbdisc32_kernel(const float* __restrict__ Ms,
                                                       const unsigned short* __restrict__ Msb,
                                                       const float* __restrict__ nrm,
                                                       float* __restrict__ outT) {
    extern __shared__ char smem[];                       // 32KB slab + 4KB nrm
    float* Nlds = (float*)(smem + 32768);

    const int t    = threadIdx.x;
    const int lane = t & 63;
    const int w    = t >> 6;                             // 0..7
    const int b    = blockIdx.y;
    const int bx   = blockIdx.x;                         // i-half / role
    const int bz   = blockIdx.z;
    const int cl   = lane & 31;
    const int hk   = lane >> 5;
    const int diag = (bx == bz);
    const int jh   = bx | bz;
    const int jbase = jh * 1024;

    const unsigned short* Mb = Msb + (size_t)b * NROWS * 16;
    const float* nb = nrm + (size_t)b * NROWS;

    // stage slab half: slot s = h*1024 + jj -> lds byte s*16
    #pragma unroll
    for (int q = 0; q < 4; ++q) {
        const int slot = q * 512 + t;
        const int h = slot >> 10, jj = slot & 1023;
        const unsigned short* src = Mb + (size_t)(jbase + jj) * 16 + h * 8;
        __builtin_amdgcn_global_load_lds(
            (const __attribute__((address_space(1))) void*)src,
            (__attribute__((address_space(3))) void*)(smem + (size_t)(q * 512 + w * 64) * 16),
            16, 0, 0);
    }
    if (w < 4) {   // stage j-half nrm: 1024 f32 = 4KB
        const float* src = nb + jbase + (w * 64 + lane) * 4;
        __builtin_amdgcn_global_load_lds(
            (const __attribute__((address_space(1))) void*)src,
            (__attribute__((address_space(3))) void*)(smem + 32768 + (size_t)(w * 64) * 16),
            16, 0, 0);
    }

    // i-chunk assignment (q indexes 32-row chunks of this role's i-range)
    int qs[4];
    int nq;
    if (diag) {
        qs[0] = w; qs[1] = 15 - w; qs[2] = 16 + w; qs[3] = 31 - w; nq = 4;
    } else {
        const int o = (bx == 1) ? 16 : 0;   // (1,0) takes chunks 16..31
        qs[0] = o + 2 * w; qs[1] = o + 2 * w + 1; nq = 2;
        qs[2] = qs[0]; qs[3] = qs[1];       // unused
    }
    const int ibase = diag ? bx * 1024 : 0;

    // A-frags from global (L2-hot), issued before barrier
    bf16x8 afc[4];
    #pragma unroll
    for (int qi = 0; qi < 4; ++qi) {
        const int i0 = ibase + qs[qi] * 32;
        afc[qi] = *reinterpret_cast<const bf16x8*>(Mb + (size_t)(i0 + cl) * 16 + hk * 8);
    }
    __syncthreads();

    const char* mrow = smem + hk * 16384;

    for (int qi = 0; qi < nq; ++qi) {
        const int q  = qs[qi];
        const int i0 = ibase + q * 32;
        const bf16x8 af = afc[qi];

        // loop-invariant C-in: cI[r] = 725 - 0.495 n_i
        f32x16 cI;
        #pragma unroll
        for (int p = 0; p < 4; ++p) {
            const float4 v = *reinterpret_cast<const float4*>(nb + i0 + 4 * hk + 8 * p);
            cI[4 * p + 0] = 725.f - v.x; cI[4 * p + 1] = 725.f - v.y;
            cI[4 * p + 2] = 725.f - v.z; cI[4 * p + 3] = 725.f - v.w;
        }

        const int jt0 = diag ? q : 0;
        #pragma unroll 2
        for (int jt = jt0; jt < 32; ++jt) {
            const int j0 = jt * 32;
            const float njv  = Nlds[j0 + cl];
            const bf16x8 bfr = *reinterpret_cast<const bf16x8*>(mrow + (size_t)(j0 + cl) * 16);
            const f32x16 acc = __builtin_amdgcn_mfma_f32_32x32x16_bf16(af, bfr, cI, 0, 0, 0);

            const float p0 = fmaxf(fmaxf(acc[0],  acc[1]),  acc[2]);
            const float p1 = fmaxf(fmaxf(acc[3],  acc[4]),  acc[5]);
            const float p2 = fmaxf(fmaxf(acc[6],  acc[7]),  acc[8]);
            const float p3 = fmaxf(fmaxf(acc[9],  acc[10]), acc[11]);
            const float p4 = fmaxf(fmaxf(acc[12], acc[13]), acc[14]);
            const float mx = fmaxf(fmaxf(fmaxf(p0, p1), acc[15]),
                                   fmaxf(fmaxf(p2, p3), p4));

            if (__any(mx > njv)) {
                #pragma unroll
                for (int r = 0; r < 16; ++r) {
                    if (acc[r] > njv) {
                        const int i = i0 + (r & 3) + 8 * (r >> 2) + 4 * hk;
                        const int j = jbase + j0 + cl;
                        if (j > i) {
                            const float* pi = Ms + (size_t)i * 2048 + b * 16;
                            const float* pj = Ms + (size_t)j * 2048 + b * 16;
                            float s = 0.f;
                            #pragma unroll
                            for (int cc = 0; cc < 16; cc += 4) {
                                const float4 x = *reinterpret_cast<const float4*>(pi + cc);
                                const float4 y = *reinterpret_cast<const float4*>(pj + cc);
                                s += (fabsf(x.x - y.x) + fabsf(x.y - y.y)) +
                                     (fabsf(x.z - y.z) + fabsf(x.w - y.w));
                            }
                            const float e = __expf(-s);
                            atomicAdd(&outT[(size_t)i * DBx + b], e);
                            atomicAdd(&outT[(size_t)j * DBx + b], e);
                        }
                    }
                }
            }
        }
    }
}

// ---------------------------------------------------------------------------
// logits = sigmoid(concat(feature, outT) @ Wo + bo). One block per row.
// ---------------------------------------------------------------------------
__global__ __launch_bounds__(256) void logits_kernel(const float* __restrict__ feat,
                                                     const float* __restrict__ outT,
                                                     const float* __restrict__ Wo,
                                                     const float* __restrict__ bo,
                                                     float* __restrict__ out2) {
    const int row = blockIdx.x;
    const int t   = threadIdx.x;
    float p = 0.f;
    for (int k = t; k < HD + DBx; k += 256) {
        const float x = (k < HD) ? feat[(size_t)row * HD + k]
                                 : outT[(size_t)row * DBx + (k - HD)];
        p += x * Wo[k];
    }
    #pragma unroll
    for (int off = 32; off; off >>= 1) p += __shfl_down(p, off, 64);
    __shared__ float ws[4];
    if ((t & 63) == 0) ws[t >> 6] = p;
    __syncthreads();
    if (t == 0) {
        const float s = ws[0] + ws[1] + ws[2] + ws[3] + bo[0];
        out2[row] = 1.f / (1.f + __expf(-s));
    }
}

// ---------------------------------------------------------------------------
extern "C" void kernel_launch(void* const* d_in, const int* in_sizes, int n_in,
                              void* d_out, int out_size, void* d_ws, size_t ws_size,
                              hipStream_t stream) {
    const float* input = (const float*)d_in[0];
    const float* W1 = (const float*)d_in[1];
    const float* b1 = (const float*)d_in[2];
    const float* W2 = (const float*)d_in[3];
    const float* b2 = (const float*)d_in[4];
    const float* Wh = (const float*)d_in[5];
    const float* bh = (const float*)d_in[6];
    const float* W3 = (const float*)d_in[7];
    const float* b3 = (const float*)d_in[8];
    const float* W4 = (const float*)d_in[9];
    const float* b4 = (const float*)d_in[10];
    const float* Wo = (const float*)d_in[11];
    const float* bo = (const float*)d_in[12];
    const float* T  = (const float*)d_in[13];

    unsigned short* inbf  = (unsigned short*)d_ws;                 // 2 MB
    unsigned short* W1t   = inbf  + (size_t)2048 * 512;            // 1 MB
    unsigned short* W2t   = W1t   + (size_t)1024 * 512;            // 3 MB
    unsigned short* Wht   = W2t   + (size_t)1536 * 1024;           // 4.5 MB
    unsigned short* W3t   = Wht   + (size_t)1536 * 1536;           // 3 MB
    unsigned short* W4t   = W3t   + (size_t)1024 * 1536;           // 1 MB
    unsigned short* Tt    = W4t   + (size_t)512 * 1024;            // 2 MB
    unsigned short* slabA = Tt    + (size_t)2048 * 512;            // 6 MB
    unsigned short* slabB = slabA + (size_t)2048 * 1536;           // 6 MB
    float* Ms  = (float*)(slabB + (size_t)2048 * 1536);            // 16 MB
    float* oT  = Ms + (size_t)2048 * 2048;                         // 1 MB
    float* nrm = oT + (size_t)2048 * 128;                          // 1 MB
    unsigned short* Msb = inbf;  // 8 MB, region dead by T-GEMM time

    unsigned short* x1bf   = slabA;
    unsigned short* x2bf   = slabB;
    unsigned short* x3bf   = slabA;
    unsigned short* x4bf   = slabB;
    unsigned short* featbf = slabA;

    float* feat = (float*)d_out;
    float* out2 = feat + (size_t)NROWS * HD;

    const dim3 blk(256);

    TransArgs ta;
    ta.src[0] = W1; ta.dst[0] = W1t; ta.K[0] =  512; ta.M[0] = 1024; ta.t0[0] = 0;
    ta.src[1] = W2; ta.dst[1] = W2t; ta.K[1] = 1024; ta.M[1] = 1536; ta.t0[1] = 512;
    ta.src[2] = Wh; ta.dst[2] = Wht; ta.K[2] = 1536; ta.M[2] = 1536; ta.t0[2] = 2048;
    ta.src[3] = W3; ta.dst[3] = W3t; ta.K[3] = 1536; ta.M[3] = 1024; ta.t0[3] = 4352;
    ta.src[4] = W4; ta.dst[4] = W4t; ta.K[4] = 1024; ta.M[4] =  512; ta.t0[4] = 5888;
    ta.src[5] = T;  ta.dst[5] = Tt;  ta.K[5] =  512; ta.M[5] = 2048; ta.t0[5] = 6400;
    trans_all_kernel<<<TRANS_BLOCKS + CONV_BLOCKS, blk, 0, stream>>>(ta, input, inbf);

    gemm64_kernel<1, 0, 1, 1, 0><<<dim3(1024 / 64, 32), blk, 0, stream>>>(inbf, W1t, b1, x1bf, nullptr, 512, 1024);
    gemm64_kernel<1, 0, 1, 1, 0><<<dim3(1536 / 64, 32), blk, 0, stream>>>(x1bf, W2t, b2, x2bf, nullptr, 1024, 1536);
    gemm64_kernel<1, 0, 1, 1, 0><<<dim3(1536 / 64, 32), blk, 0, stream>>>(x2bf, Wht, bh, x3bf, nullptr, 1536, 1536);
    gemm64_kernel<1, 0, 1, 1, 0><<<dim3(1024 / 64, 32), blk, 0, stream>>>(x3bf, W3t, b3, x4bf, nullptr, 1536, 1024);
    gemm64_kernel<1, 1, 1, 1, 0><<<dim3( 512 / 64, 32), blk, 0, stream>>>(x4bf, W4t, b4, featbf, feat, 1024, 512);
    gemm64_kernel<1, 1, 0, 0, 1><<<dim3(2048 / 64, 32), blk, 0, stream>>>(featbf, Tt, nullptr, Msb, Ms, 512, 2048);

    norms_kernel<<<1024, blk, 0, stream>>>(Ms, nrm, oT);
    mbdisc32_kernel<<<dim3(2, 128, 2), dim3(512), 36864, stream>>>(Ms, Msb, nrm, oT);

    logits_kernel<<<NROWS, blk, 0, stream>>>(feat, oT, Wo, bo, out2);
}